// Round 2
// baseline (852.335 us; speedup 1.0000x reference)
//
#include <hip/hip_runtime.h>

#define D_DIM 1024
#define H_DIM 1024
#define E_NUM 8
#define BM 128
#define BN 128
#define BK 64

typedef __attribute__((ext_vector_type(8))) _Float16 h8v;
typedef __attribute__((ext_vector_type(4))) float f4v;

__device__ __forceinline__ unsigned short f2h(float f) {
  union { _Float16 h; unsigned short u; } c;
  c.h = (_Float16)f;  // v_cvt_f16_f32, RNE
  return c.u;
}

// ---------------- phase 0a: x fp32 -> fp16 ----------------
__global__ void convert_x_kernel(const float4* __restrict__ x,
                                 unsigned short* __restrict__ xh, int n4) {
  int i = blockIdx.x * blockDim.x + threadIdx.x;
  if (i >= n4) return;
  float4 v = x[i];
  ushort4 o;
  o.x = f2h(v.x); o.y = f2h(v.y); o.z = f2h(v.z); o.w = f2h(v.w);
  *(ushort4*)(xh + (size_t)i * 4) = o;
}

// ---------------- phase 0b: W [E][D][H] fp32 -> Wt [E][H][D] fp16 ----------------
__global__ void transpose_w_kernel(const float* __restrict__ W,
                                   unsigned short* __restrict__ Wt) {
  __shared__ float tile[32][33];
  int e = blockIdx.z;
  int h0 = blockIdx.x * 32, d0 = blockIdx.y * 32;
  const float* Wp = W + (size_t)e * D_DIM * H_DIM;
  unsigned short* Wtp = Wt + (size_t)e * H_DIM * D_DIM;
#pragma unroll
  for (int j = 0; j < 32; j += 8)
    tile[threadIdx.y + j][threadIdx.x] =
        Wp[(size_t)(d0 + threadIdx.y + j) * H_DIM + (h0 + threadIdx.x)];
  __syncthreads();
#pragma unroll
  for (int j = 0; j < 32; j += 8)
    Wtp[(size_t)(h0 + threadIdx.y + j) * D_DIM + (d0 + threadIdx.x)] =
        f2h(tile[threadIdx.x][threadIdx.y + j]);
}

// ---------------- phase 1: router (fp32, exact top-2) ----------------
__global__ __launch_bounds__(256) void router_kernel(
    const float* __restrict__ x, const float* __restrict__ gw,
    const float* __restrict__ gb, int* __restrict__ counts,
    int* __restrict__ bucket, float* __restrict__ scoreB, int B) {
  __shared__ float gwS[E_NUM * D_DIM];  // 32 KB, reused by 16 tokens/block
  int tid = threadIdx.x;
  for (int i = tid; i < E_NUM * D_DIM; i += 256) gwS[i] = gw[i];
  __syncthreads();
  int wid = tid >> 6, lane = tid & 63;
  for (int rep = 0; rep < 4; rep++) {
    int b = blockIdx.x * 16 + wid * 4 + rep;
    float acc[E_NUM];
#pragma unroll
    for (int e = 0; e < E_NUM; e++) acc[e] = 0.0f;
#pragma unroll
    for (int i = 0; i < D_DIM / 64; i++) {
      float xv = x[(size_t)b * D_DIM + i * 64 + lane];
#pragma unroll
      for (int e = 0; e < E_NUM; e++) acc[e] += xv * gwS[e * D_DIM + i * 64 + lane];
    }
#pragma unroll
    for (int e = 0; e < E_NUM; e++) {
#pragma unroll
      for (int off = 32; off > 0; off >>= 1) acc[e] += __shfl_down(acc[e], off);
    }
    if (lane == 0) {
      float l[E_NUM];
#pragma unroll
      for (int e = 0; e < E_NUM; e++) l[e] = acc[e] + gb[e];
      int i0 = 0;
#pragma unroll
      for (int e = 1; e < E_NUM; e++) if (l[e] > l[i0]) i0 = e;
      int i1 = (i0 == 0) ? 1 : 0;
#pragma unroll
      for (int e = 0; e < E_NUM; e++) if (e != i0 && l[e] > l[i1]) i1 = e;
      float mx = l[i0];
      float denom = 0.0f;
#pragma unroll
      for (int e = 0; e < E_NUM; e++) denom += __expf(l[e] - mx);
      float s0 = 1.0f / denom;                 // exp(0)/denom
      float s1 = __expf(l[i1] - mx) / denom;
      int p0 = atomicAdd(&counts[i0], 1);
      bucket[i0 * B + p0] = b;
      scoreB[i0 * B + p0] = s0;
      int p1 = atomicAdd(&counts[i1], 1);
      bucket[i1 * B + p1] = b;
      scoreB[i1 * B + p1] = s1;
    }
  }
}

// ---------------- phase 2: grouped dual-GEMM + SwiGLU + scatter ----------------
// LDS layout: [row][k], 16B chunk c stored at chunk (c ^ (row&7)) -> conflict-free
// ds_read_b128 fragment reads AND conflict-free staging writes.
__global__ __launch_bounds__(256, 2) void moe_gemm_kernel(
    const unsigned short* __restrict__ xh, const unsigned short* __restrict__ Wvt,
    const unsigned short* __restrict__ Wgt, const int* __restrict__ counts,
    const int* __restrict__ bucket, const float* __restrict__ scoreB,
    float* __restrict__ out, int B) {
  int e = blockIdx.z;
  int cnt = counts[e];
  int m0 = blockIdx.x * BM;
  if (m0 >= cnt) return;
  int n0 = blockIdx.y * BN;

  __shared__ unsigned short As[BM * BK];
  __shared__ unsigned short Bvs[BN * BK];
  __shared__ unsigned short Bgs[BN * BK];
  __shared__ int tokS[BM];
  __shared__ float scS[BM];

  int tid = threadIdx.x;
  if (tid < BM) {
    int gr = m0 + tid;
    bool vld = gr < cnt;
    tokS[tid] = vld ? bucket[e * B + gr] : 0;
    scS[tid] = vld ? scoreB[e * B + gr] : 0.0f;  // padded rows contribute 0
  }
  __syncthreads();

  int wid = tid >> 6, lane = tid & 63;
  int wm = wid & 1, wn = wid >> 1;
  int quad = lane >> 4, lr = lane & 15;

  f4v accv[4][4], accg[4][4];
#pragma unroll
  for (int a = 0; a < 4; a++)
#pragma unroll
    for (int bb = 0; bb < 4; bb++) {
      f4v z = {0.f, 0.f, 0.f, 0.f};
      accv[a][bb] = z;
      accg[a][bb] = z;
    }

  const unsigned short* Bv0 = Wvt + (size_t)(e * H_DIM + n0) * D_DIM;
  const unsigned short* Bg0 = Wgt + (size_t)(e * H_DIM + n0) * D_DIM;

  for (int kt = 0; kt < D_DIM / BK; kt++) {
    int k0 = kt * BK;
    uint4 va[4], vb[4], vg[4];
#pragma unroll
    for (int i = 0; i < 4; i++) {
      int id = tid + 256 * i;
      int row = id >> 3, c = id & 7;
      int tok = tokS[row];
      va[i] = *(const uint4*)(xh + (size_t)tok * D_DIM + k0 + c * 8);
      vb[i] = *(const uint4*)(Bv0 + (size_t)row * D_DIM + k0 + c * 8);
      vg[i] = *(const uint4*)(Bg0 + (size_t)row * D_DIM + k0 + c * 8);
    }
#pragma unroll
    for (int i = 0; i < 4; i++) {
      int id = tid + 256 * i;
      int row = id >> 3, c = id & 7;
      int off = row * BK + ((c ^ (row & 7)) * 8);
      *(uint4*)(As + off) = va[i];
      *(uint4*)(Bvs + off) = vb[i];
      *(uint4*)(Bgs + off) = vg[i];
    }
    __syncthreads();

    h8v af[4][2], bfr[4][2];
#pragma unroll
    for (int fm = 0; fm < 4; fm++)
#pragma unroll
      for (int s = 0; s < 2; s++) {
        int row = wm * 64 + fm * 16 + lr;
        int c = s * 4 + quad;
        af[fm][s] = *(const h8v*)(As + row * BK + ((c ^ (row & 7)) * 8));
      }
#pragma unroll
    for (int fn = 0; fn < 4; fn++)
#pragma unroll
      for (int s = 0; s < 2; s++) {
        int row = wn * 64 + fn * 16 + lr;
        int c = s * 4 + quad;
        bfr[fn][s] = *(const h8v*)(Bvs + row * BK + ((c ^ (row & 7)) * 8));
      }
#pragma unroll
    for (int fm = 0; fm < 4; fm++)
#pragma unroll
      for (int fn = 0; fn < 4; fn++)
#pragma unroll
        for (int s = 0; s < 2; s++)
          accv[fm][fn] = __builtin_amdgcn_mfma_f32_16x16x32_f16(
              af[fm][s], bfr[fn][s], accv[fm][fn], 0, 0, 0);
#pragma unroll
    for (int fn = 0; fn < 4; fn++)
#pragma unroll
      for (int s = 0; s < 2; s++) {
        int row = wn * 64 + fn * 16 + lr;
        int c = s * 4 + quad;
        bfr[fn][s] = *(const h8v*)(Bgs + row * BK + ((c ^ (row & 7)) * 8));
      }
#pragma unroll
    for (int fm = 0; fm < 4; fm++)
#pragma unroll
      for (int fn = 0; fn < 4; fn++)
#pragma unroll
        for (int s = 0; s < 2; s++)
          accg[fm][fn] = __builtin_amdgcn_mfma_f32_16x16x32_f16(
              af[fm][s], bfr[fn][s], accg[fm][fn], 0, 0, 0);
    __syncthreads();
  }

  // epilogue: act = v * sigmoid(g) * score, scatter-add to out[token]
  // C/D layout: col = lane&15, row = quad*4 + reg  [measured m89/m91; dtype-independent]
#pragma unroll
  for (int fm = 0; fm < 4; fm++) {
#pragma unroll
    for (int r = 0; r < 4; r++) {
      int row = wm * 64 + fm * 16 + quad * 4 + r;
      int tok = tokS[row];
      float sc = scS[row];
#pragma unroll
      for (int fn = 0; fn < 4; fn++) {
        int col = n0 + wn * 64 + fn * 16 + lr;
        float v = accv[fm][fn][r];
        float g = accg[fm][fn][r];
        float act = v * sc / (1.0f + __expf(-g));
        atomicAdd(&out[(size_t)tok * H_DIM + col], act);
      }
    }
  }
}

extern "C" void kernel_launch(void* const* d_in, const int* in_sizes, int n_in,
                              void* d_out, int out_size, void* d_ws, size_t ws_size,
                              hipStream_t stream) {
  const float* x = (const float*)d_in[0];
  const float* Wv = (const float*)d_in[1];
  const float* Wg = (const float*)d_in[2];
  const float* gw = (const float*)d_in[3];
  const float* gb = (const float*)d_in[4];
  float* out = (float*)d_out;
  const int B = in_sizes[0] / D_DIM;  // 16384

  char* ws = (char*)d_ws;
  unsigned short* xh = (unsigned short*)ws;                       // B*D*2 = 32 MB
  size_t off = (size_t)B * D_DIM * 2;
  unsigned short* Wvt = (unsigned short*)(ws + off);              // 16 MB
  off += (size_t)E_NUM * H_DIM * D_DIM * 2;
  unsigned short* Wgt = (unsigned short*)(ws + off);              // 16 MB
  off += (size_t)E_NUM * H_DIM * D_DIM * 2;
  int* counts = (int*)(ws + off);                                 // 8 ints (pad 256)
  off += 256;
  int* bucket = (int*)(ws + off);                                 // E*B ints
  off += (size_t)E_NUM * B * 4;
  float* scoreB = (float*)(ws + off);                             // E*B floats

  hipMemsetAsync(d_out, 0, (size_t)out_size * 4, stream);
  hipMemsetAsync(counts, 0, 256, stream);

  int n4 = B * D_DIM / 4;
  convert_x_kernel<<<(n4 + 255) / 256, 256, 0, stream>>>((const float4*)x, xh, n4);
  transpose_w_kernel<<<dim3(H_DIM / 32, D_DIM / 32, E_NUM), dim3(32, 8), 0, stream>>>(Wv, Wvt);
  transpose_w_kernel<<<dim3(H_DIM / 32, D_DIM / 32, E_NUM), dim3(32, 8), 0, stream>>>(Wg, Wgt);
  router_kernel<<<B / 16, 256, 0, stream>>>(x, gw, gb, counts, bucket, scoreB, B);
  moe_gemm_kernel<<<dim3(B / BM, H_DIM / BN, E_NUM), 256, 0, stream>>>(
      xh, Wvt, Wgt, counts, bucket, scoreB, out, B);
}

// Round 3
// 390.639 us; speedup vs baseline: 2.1819x; 2.1819x over previous
//
#include <hip/hip_runtime.h>

#define D_DIM 1024
#define H_DIM 1024
#define E_NUM 8
#define BM 128
#define BN 128
#define BK 64
#define CAP 5120      // per-expert bucket capacity (mean 4096, sigma ~55; >18 sigma)
#define RT_TOK 32     // tokens per router block

typedef __attribute__((ext_vector_type(8))) _Float16 h8v;
typedef __attribute__((ext_vector_type(4))) _Float16 h4v;
typedef __attribute__((ext_vector_type(4))) float f4v;

__device__ __forceinline__ unsigned short f2h(float f) {
  union { _Float16 h; unsigned short u; } c;
  c.h = (_Float16)f;  // v_cvt_f16_f32, RNE
  return c.u;
}

// ---------------- phase 0a: x fp32 -> fp16 ----------------
__global__ void convert_x_kernel(const float4* __restrict__ x,
                                 unsigned short* __restrict__ xh, int n4) {
  int i = blockIdx.x * blockDim.x + threadIdx.x;
  if (i >= n4) return;
  float4 v = x[i];
  ushort4 o;
  o.x = f2h(v.x); o.y = f2h(v.y); o.z = f2h(v.z); o.w = f2h(v.w);
  *(ushort4*)(xh + (size_t)i * 4) = o;
}

// ---------------- phase 0b: W [E][D][H] fp32 -> Wt [E][H][D] fp16 ----------------
__global__ void transpose_w_kernel(const float* __restrict__ W,
                                   unsigned short* __restrict__ Wt) {
  __shared__ float tile[32][33];
  int e = blockIdx.z;
  int h0 = blockIdx.x * 32, d0 = blockIdx.y * 32;
  const float* Wp = W + (size_t)e * D_DIM * H_DIM;
  unsigned short* Wtp = Wt + (size_t)e * H_DIM * D_DIM;
#pragma unroll
  for (int j = 0; j < 32; j += 8)
    tile[threadIdx.y + j][threadIdx.x] =
        Wp[(size_t)(d0 + threadIdx.y + j) * H_DIM + (h0 + threadIdx.x)];
  __syncthreads();
#pragma unroll
  for (int j = 0; j < 32; j += 8)
    Wtp[(size_t)(h0 + threadIdx.y + j) * D_DIM + (d0 + threadIdx.x)] =
        f2h(tile[threadIdx.x][threadIdx.y + j]);
}

// ---------------- phase 1: router (fp32, exact top-2, block-aggregated scatter) ----
// counts[] padded: expert e at counts[e*32] (128 B apart -> no line contention).
__global__ __launch_bounds__(256) void router_kernel(
    const float4* __restrict__ x4, const float4* __restrict__ gw4,
    const float* __restrict__ gb, int* __restrict__ counts,
    int* __restrict__ bucket, float* __restrict__ scoreB,
    int* __restrict__ slotOf, int B) {
  __shared__ float4 gwS[E_NUM * 256];  // 32 KB: all 8 expert rows
  __shared__ short eSelS[RT_TOK][2];
  __shared__ float sSelS[RT_TOK][2];
  __shared__ int lCnt[E_NUM], lBase[E_NUM];
  __shared__ unsigned char lOff[RT_TOK][2];
  int tid = threadIdx.x;
  for (int i = tid; i < E_NUM * 256; i += 256) gwS[i] = gw4[i];
  if (tid < E_NUM) lCnt[tid] = 0;
  __syncthreads();
  int wid = tid >> 6, lane = tid & 63;
  for (int rep = 0; rep < RT_TOK / 4; rep++) {
    int t = wid * (RT_TOK / 4) + rep;
    int b = blockIdx.x * RT_TOK + t;
    float acc[E_NUM];
#pragma unroll
    for (int e = 0; e < E_NUM; e++) acc[e] = 0.0f;
#pragma unroll
    for (int i = 0; i < 4; i++) {  // k = (i*64+lane)*4 .. +3
      float4 xv = x4[(size_t)b * 256 + i * 64 + lane];
#pragma unroll
      for (int e = 0; e < E_NUM; e++) {
        float4 w = gwS[e * 256 + i * 64 + lane];
        acc[e] += xv.x * w.x + xv.y * w.y + xv.z * w.z + xv.w * w.w;
      }
    }
#pragma unroll
    for (int e = 0; e < E_NUM; e++) {
#pragma unroll
      for (int off = 32; off > 0; off >>= 1) acc[e] += __shfl_down(acc[e], off);
    }
    if (lane == 0) {
      float l[E_NUM];
#pragma unroll
      for (int e = 0; e < E_NUM; e++) l[e] = acc[e] + gb[e];
      int i0 = 0;
#pragma unroll
      for (int e = 1; e < E_NUM; e++) if (l[e] > l[i0]) i0 = e;
      int i1 = (i0 == 0) ? 1 : 0;
#pragma unroll
      for (int e = 0; e < E_NUM; e++) if (e != i0 && l[e] > l[i1]) i1 = e;
      float mx = l[i0];
      float denom = 0.0f;
#pragma unroll
      for (int e = 0; e < E_NUM; e++) denom += __expf(l[e] - mx);
      eSelS[t][0] = (short)i0; sSelS[t][0] = 1.0f / denom;
      eSelS[t][1] = (short)i1; sSelS[t][1] = __expf(l[i1] - mx) / denom;
    }
  }
  __syncthreads();
  if (tid < RT_TOK) {
    lOff[tid][0] = (unsigned char)atomicAdd(&lCnt[eSelS[tid][0]], 1);
    lOff[tid][1] = (unsigned char)atomicAdd(&lCnt[eSelS[tid][1]], 1);
  }
  __syncthreads();
  if (tid < E_NUM) lBase[tid] = atomicAdd(&counts[tid * 32], lCnt[tid]);
  __syncthreads();
  if (tid < RT_TOK) {
    int b = blockIdx.x * RT_TOK + tid;
#pragma unroll
    for (int j = 0; j < 2; j++) {
      int e = eSelS[tid][j];
      int pos = lBase[e] + lOff[tid][j];
      if (pos < CAP) {
        int slot = e * CAP + pos;
        bucket[slot] = b;
        scoreB[slot] = sSelS[tid][j];
        slotOf[b * 2 + j] = slot;
      }
    }
  }
}

// ---------------- phase 2: grouped dual-GEMM + SwiGLU ----------------
// LDS layout: [row][k], 16B chunk c stored at chunk (c ^ (row&7)) -> conflict-free
// ds_read_b128 fragment reads AND conflict-free staging writes.
// USE_PARTIAL: store fp16 act to partial[slot][col] (no atomics; gather sums later).
// else: fp32 atomicAdd into out (fallback when ws is small).
template <bool USE_PARTIAL>
__global__ __launch_bounds__(256, 2) void moe_gemm_kernel(
    const unsigned short* __restrict__ xh, const unsigned short* __restrict__ Wvt,
    const unsigned short* __restrict__ Wgt, const int* __restrict__ counts,
    const int* __restrict__ bucket, const float* __restrict__ scoreB,
    _Float16* __restrict__ partial, float* __restrict__ out, int B) {
  int e = blockIdx.z;
  int cnt = counts[e * 32];
  int m0 = blockIdx.x * BM;
  if (m0 >= cnt) return;
  int n0 = blockIdx.y * BN;

  __shared__ unsigned short As[BM * BK];
  __shared__ unsigned short Bvs[BN * BK];
  __shared__ unsigned short Bgs[BN * BK];
  __shared__ int tokS[BM];
  __shared__ float scS[BM];

  int tid = threadIdx.x;
  if (tid < BM) {
    int gr = m0 + tid;
    bool vld = gr < cnt;
    tokS[tid] = vld ? bucket[e * CAP + gr] : 0;
    scS[tid] = vld ? scoreB[e * CAP + gr] : 0.0f;  // padded rows contribute 0
  }
  __syncthreads();

  int wid = tid >> 6, lane = tid & 63;
  int wm = wid & 1, wn = wid >> 1;
  int quad = lane >> 4, lr = lane & 15;

  f4v accv[4][4], accg[4][4];
#pragma unroll
  for (int a = 0; a < 4; a++)
#pragma unroll
    for (int bb = 0; bb < 4; bb++) {
      f4v z = {0.f, 0.f, 0.f, 0.f};
      accv[a][bb] = z;
      accg[a][bb] = z;
    }

  const unsigned short* Bv0 = Wvt + (size_t)(e * H_DIM + n0) * D_DIM;
  const unsigned short* Bg0 = Wgt + (size_t)(e * H_DIM + n0) * D_DIM;

  for (int kt = 0; kt < D_DIM / BK; kt++) {
    int k0 = kt * BK;
    uint4 va[4], vb[4], vg[4];
#pragma unroll
    for (int i = 0; i < 4; i++) {
      int id = tid + 256 * i;
      int row = id >> 3, c = id & 7;
      int tok = tokS[row];
      va[i] = *(const uint4*)(xh + (size_t)tok * D_DIM + k0 + c * 8);
      vb[i] = *(const uint4*)(Bv0 + (size_t)row * D_DIM + k0 + c * 8);
      vg[i] = *(const uint4*)(Bg0 + (size_t)row * D_DIM + k0 + c * 8);
    }
#pragma unroll
    for (int i = 0; i < 4; i++) {
      int id = tid + 256 * i;
      int row = id >> 3, c = id & 7;
      int off = row * BK + ((c ^ (row & 7)) * 8);
      *(uint4*)(As + off) = va[i];
      *(uint4*)(Bvs + off) = vb[i];
      *(uint4*)(Bgs + off) = vg[i];
    }
    __syncthreads();

    h8v af[4][2], bfr[4][2];
#pragma unroll
    for (int fm = 0; fm < 4; fm++)
#pragma unroll
      for (int s = 0; s < 2; s++) {
        int row = wm * 64 + fm * 16 + lr;
        int c = s * 4 + quad;
        af[fm][s] = *(const h8v*)(As + row * BK + ((c ^ (row & 7)) * 8));
      }
#pragma unroll
    for (int fn = 0; fn < 4; fn++)
#pragma unroll
      for (int s = 0; s < 2; s++) {
        int row = wn * 64 + fn * 16 + lr;
        int c = s * 4 + quad;
        bfr[fn][s] = *(const h8v*)(Bvs + row * BK + ((c ^ (row & 7)) * 8));
      }
#pragma unroll
    for (int fm = 0; fm < 4; fm++)
#pragma unroll
      for (int fn = 0; fn < 4; fn++)
#pragma unroll
        for (int s = 0; s < 2; s++)
          accv[fm][fn] = __builtin_amdgcn_mfma_f32_16x16x32_f16(
              af[fm][s], bfr[fn][s], accv[fm][fn], 0, 0, 0);
#pragma unroll
    for (int fn = 0; fn < 4; fn++)
#pragma unroll
      for (int s = 0; s < 2; s++) {
        int row = wn * 64 + fn * 16 + lr;
        int c = s * 4 + quad;
        bfr[fn][s] = *(const h8v*)(Bgs + row * BK + ((c ^ (row & 7)) * 8));
      }
#pragma unroll
    for (int fm = 0; fm < 4; fm++)
#pragma unroll
      for (int fn = 0; fn < 4; fn++)
#pragma unroll
        for (int s = 0; s < 2; s++)
          accg[fm][fn] = __builtin_amdgcn_mfma_f32_16x16x32_f16(
              af[fm][s], bfr[fn][s], accg[fm][fn], 0, 0, 0);
    __syncthreads();
  }

  // epilogue: act = v * sigmoid(g) * score
  // C/D layout: col = lane&15, row = quad*4 + reg  [measured m89/m91; dtype-independent]
#pragma unroll
  for (int fm = 0; fm < 4; fm++) {
#pragma unroll
    for (int r = 0; r < 4; r++) {
      int row = wm * 64 + fm * 16 + quad * 4 + r;
      float sc = scS[row];
      if (USE_PARTIAL) {
        // padded rows (gr>=cnt) write sc=0 into never-read slots: no mask needed
        int slot = e * CAP + m0 + row;
        _Float16* pr = partial + (size_t)slot * H_DIM;
#pragma unroll
        for (int fn = 0; fn < 4; fn++) {
          int col = n0 + wn * 64 + fn * 16 + lr;
          float v = accv[fm][fn][r];
          float g = accg[fm][fn][r];
          pr[col] = (_Float16)(v * sc / (1.0f + __expf(-g)));
        }
      } else {
        int tok = tokS[row];
#pragma unroll
        for (int fn = 0; fn < 4; fn++) {
          int col = n0 + wn * 64 + fn * 16 + lr;
          float v = accv[fm][fn][r];
          float g = accg[fm][fn][r];
          atomicAdd(&out[(size_t)tok * H_DIM + col], v * sc / (1.0f + __expf(-g)));
        }
      }
    }
  }
}

// ---------------- phase 3: gather (out[b] = partial[s0] + partial[s1]) ----------
__global__ __launch_bounds__(256) void gather_kernel(
    const _Float16* __restrict__ partial, const int* __restrict__ slotOf,
    float* __restrict__ out) {
  int b = blockIdx.x;  // one token per block, 256 threads x 4 cols
  int tid = threadIdx.x;
  int s0 = slotOf[b * 2], s1 = slotOf[b * 2 + 1];
  h4v a = ((const h4v*)(partial + (size_t)s0 * H_DIM))[tid];
  h4v c = ((const h4v*)(partial + (size_t)s1 * H_DIM))[tid];
  float4 o;
  o.x = (float)a[0] + (float)c[0];
  o.y = (float)a[1] + (float)c[1];
  o.z = (float)a[2] + (float)c[2];
  o.w = (float)a[3] + (float)c[3];
  ((float4*)(out + (size_t)b * H_DIM))[tid] = o;
}

extern "C" void kernel_launch(void* const* d_in, const int* in_sizes, int n_in,
                              void* d_out, int out_size, void* d_ws, size_t ws_size,
                              hipStream_t stream) {
  const float* x = (const float*)d_in[0];
  const float* Wv = (const float*)d_in[1];
  const float* Wg = (const float*)d_in[2];
  const float* gw = (const float*)d_in[3];
  const float* gb = (const float*)d_in[4];
  float* out = (float*)d_out;
  const int B = in_sizes[0] / D_DIM;  // 16384

  char* ws = (char*)d_ws;
  unsigned short* xh = (unsigned short*)ws;                       // 32 MB
  size_t off = (size_t)B * D_DIM * 2;
  unsigned short* Wvt = (unsigned short*)(ws + off);              // 16 MB
  off += (size_t)E_NUM * H_DIM * D_DIM * 2;
  unsigned short* Wgt = (unsigned short*)(ws + off);              // 16 MB
  off += (size_t)E_NUM * H_DIM * D_DIM * 2;
  int* counts = (int*)(ws + off);                                 // 8 padded counters
  off += 4096;
  int* bucket = (int*)(ws + off);                                 // E*CAP ints
  off += (size_t)E_NUM * CAP * 4;
  float* scoreB = (float*)(ws + off);                             // E*CAP floats
  off += (size_t)E_NUM * CAP * 4;
  int* slotOf = (int*)(ws + off);                                 // B*2 ints
  off += (size_t)B * 2 * 4;
  _Float16* partial = (_Float16*)(ws + off);                      // E*CAP*H fp16 = 80 MB
  size_t need = off + (size_t)E_NUM * CAP * H_DIM * 2;
  bool use_partial = ws_size >= need;

  hipMemsetAsync(counts, 0, 4096, stream);
  if (!use_partial) hipMemsetAsync(d_out, 0, (size_t)out_size * 4, stream);

  int n4 = B * D_DIM / 4;
  convert_x_kernel<<<(n4 + 255) / 256, 256, 0, stream>>>((const float4*)x, xh, n4);
  transpose_w_kernel<<<dim3(H_DIM / 32, D_DIM / 32, E_NUM), dim3(32, 8), 0, stream>>>(Wv, Wvt);
  transpose_w_kernel<<<dim3(H_DIM / 32, D_DIM / 32, E_NUM), dim3(32, 8), 0, stream>>>(Wg, Wgt);
  router_kernel<<<B / RT_TOK, 256, 0, stream>>>(
      (const float4*)x, (const float4*)gw, gb, counts, bucket, scoreB, slotOf, B);
  if (use_partial) {
    moe_gemm_kernel<true><<<dim3(CAP / BM, H_DIM / BN, E_NUM), 256, 0, stream>>>(
        xh, Wvt, Wgt, counts, bucket, scoreB, partial, out, B);
    gather_kernel<<<B, 256, 0, stream>>>(partial, slotOf, out);
  } else {
    moe_gemm_kernel<false><<<dim3(CAP / BM, H_DIM / BN, E_NUM), 256, 0, stream>>>(
        xh, Wvt, Wgt, counts, bucket, scoreB, partial, out, B);
  }
}

// Round 4
// 355.901 us; speedup vs baseline: 2.3949x; 1.0976x over previous
//
#include <hip/hip_runtime.h>

#define D_DIM 1024
#define H_DIM 1024
#define E_NUM 8
#define BM 128
#define BN 128
#define BK 64
#define CAP 5120      // per-expert bucket capacity (mean 4096, sigma ~60; >17 sigma)
#define RT_TOK 32     // tokens per router block

typedef __attribute__((ext_vector_type(8))) _Float16 h8v;
typedef __attribute__((ext_vector_type(4))) float f4v;

__device__ __forceinline__ unsigned short f2h(float f) {
  union { _Float16 h; unsigned short u; } c;
  c.h = (_Float16)f;  // v_cvt_f16_f32, RNE
  return c.u;
}

// async 16B global->LDS DMA; LDS dest = wave-uniform base + lane*16
__device__ __forceinline__ void gl2lds16(const void* g, void* l) {
  __builtin_amdgcn_global_load_lds(
      (const __attribute__((address_space(1))) unsigned int*)g,
      (__attribute__((address_space(3))) unsigned int*)l, 16, 0, 0);
}

// ---------------- phase 0: W [E][D][H] fp32 -> Wt [E][H][D] fp16 (both mats) ----
__global__ __launch_bounds__(256) void transpose_w_kernel(
    const float* __restrict__ Wv, const float* __restrict__ Wg,
    unsigned short* __restrict__ Wvt, unsigned short* __restrict__ Wgt) {
  __shared__ float tile[64][65];  // pad 65: 2-way max on both phases
  int z = blockIdx.z;             // 0..15: bit0 = which matrix, rest = expert
  const float* W = (z & 1) ? Wg : Wv;
  unsigned short* Wt = (z & 1) ? Wgt : Wvt;
  int e = z >> 1;
  int h0 = blockIdx.x * 64, d0 = blockIdx.y * 64;
  const float* Wp = W + (size_t)e * D_DIM * H_DIM;
  unsigned short* Wtp = Wt + (size_t)e * H_DIM * D_DIM;
  int t = threadIdx.x;
#pragma unroll
  for (int j = 0; j < 4; j++) {  // 1024 float4 loads, 4/thread
    int id = t + 256 * j;
    int dd = id >> 4, hc = id & 15;
    float4 v = *(const float4*)(Wp + (size_t)(d0 + dd) * H_DIM + h0 + hc * 4);
    tile[dd][hc * 4 + 0] = v.x;
    tile[dd][hc * 4 + 1] = v.y;
    tile[dd][hc * 4 + 2] = v.z;
    tile[dd][hc * 4 + 3] = v.w;
  }
  __syncthreads();
#pragma unroll
  for (int j = 0; j < 2; j++) {  // 512 uint4 (8-half) stores, 2/thread
    int id = t + 256 * j;
    int h_ = id >> 3, dc = id & 7;
    unsigned short tmp[8];
#pragma unroll
    for (int k = 0; k < 8; k++) tmp[k] = f2h(tile[dc * 8 + k][h_]);
    *(uint4*)(Wtp + (size_t)(h0 + h_) * D_DIM + d0 + dc * 8) = *(uint4*)tmp;
  }
}

// ---------------- phase 1: router (fp32 exact top-2) + fused x->fp16 convert ----
// counts[] padded: expert e at counts[e*32] (128 B apart -> no line contention).
__global__ __launch_bounds__(256) void router_kernel(
    const float4* __restrict__ x4, const float4* __restrict__ gw4,
    const float* __restrict__ gb, int* __restrict__ counts,
    int* __restrict__ bucket, float* __restrict__ scoreB,
    int* __restrict__ slotOf, ushort4* __restrict__ xh4, int B) {
  __shared__ float4 gwS[E_NUM * 256];  // 32 KB: all 8 expert rows
  __shared__ short eSelS[RT_TOK][2];
  __shared__ float sSelS[RT_TOK][2];
  __shared__ int lCnt[E_NUM], lBase[E_NUM];
  __shared__ unsigned char lOff[RT_TOK][2];
  int tid = threadIdx.x;
  for (int i = tid; i < E_NUM * 256; i += 256) gwS[i] = gw4[i];
  if (tid < E_NUM) lCnt[tid] = 0;
  __syncthreads();
  int wid = tid >> 6, lane = tid & 63;
  for (int rep = 0; rep < RT_TOK / 4; rep++) {
    int t = wid * (RT_TOK / 4) + rep;
    int b = blockIdx.x * RT_TOK + t;
    float acc[E_NUM];
#pragma unroll
    for (int e = 0; e < E_NUM; e++) acc[e] = 0.0f;
#pragma unroll
    for (int i = 0; i < 4; i++) {
      float4 xv = x4[(size_t)b * 256 + i * 64 + lane];
      ushort4 o;
      o.x = f2h(xv.x); o.y = f2h(xv.y); o.z = f2h(xv.z); o.w = f2h(xv.w);
      xh4[(size_t)b * 256 + i * 64 + lane] = o;  // fused fp16 convert
#pragma unroll
      for (int e = 0; e < E_NUM; e++) {
        float4 w = gwS[e * 256 + i * 64 + lane];
        acc[e] += xv.x * w.x + xv.y * w.y + xv.z * w.z + xv.w * w.w;
      }
    }
#pragma unroll
    for (int e = 0; e < E_NUM; e++) {
#pragma unroll
      for (int off = 32; off > 0; off >>= 1) acc[e] += __shfl_down(acc[e], off);
    }
    if (lane == 0) {
      float l[E_NUM];
#pragma unroll
      for (int e = 0; e < E_NUM; e++) l[e] = acc[e] + gb[e];
      int i0 = 0;
#pragma unroll
      for (int e = 1; e < E_NUM; e++) if (l[e] > l[i0]) i0 = e;
      int i1 = (i0 == 0) ? 1 : 0;
#pragma unroll
      for (int e = 0; e < E_NUM; e++) if (e != i0 && l[e] > l[i1]) i1 = e;
      float mx = l[i0];
      float denom = 0.0f;
#pragma unroll
      for (int e = 0; e < E_NUM; e++) denom += __expf(l[e] - mx);
      eSelS[t][0] = (short)i0; sSelS[t][0] = 1.0f / denom;
      eSelS[t][1] = (short)i1; sSelS[t][1] = __expf(l[i1] - mx) / denom;
    }
  }
  __syncthreads();
  if (tid < RT_TOK) {
    lOff[tid][0] = (unsigned char)atomicAdd(&lCnt[eSelS[tid][0]], 1);
    lOff[tid][1] = (unsigned char)atomicAdd(&lCnt[eSelS[tid][1]], 1);
  }
  __syncthreads();
  if (tid < E_NUM) lBase[tid] = atomicAdd(&counts[tid * 32], lCnt[tid]);
  __syncthreads();
  if (tid < RT_TOK) {
    int b = blockIdx.x * RT_TOK + tid;
#pragma unroll
    for (int j = 0; j < 2; j++) {
      int e = eSelS[tid][j];
      int pos = lBase[e] + lOff[tid][j];
      if (pos < CAP) {
        int slot = e * CAP + pos;
        bucket[slot] = b;
        scoreB[slot] = sSelS[tid][j];
        slotOf[b * 2 + j] = slot;
      }
    }
  }
}

// ---------------- phase 2: grouped dual-GEMM + SwiGLU ----------------
// LDS layout: [row][k], 16B chunk c stored at position (c ^ (row&7)).
// Staging via async global_load_lds: the XOR swizzle is applied to the GLOBAL
// source address per lane (lane l -> chunk (l&7)^(l>>3) of row W*8+(l>>3)),
// so the HW's linear lane*16 LDS placement lands each chunk at its swizzled
// position. Fragment ds_read_b128 stay conflict-free (2-way max).
template <bool USE_PARTIAL>
__global__ __launch_bounds__(256, 2) void moe_gemm_kernel(
    const unsigned short* __restrict__ xh, const unsigned short* __restrict__ Wvt,
    const unsigned short* __restrict__ Wgt, const int* __restrict__ counts,
    const int* __restrict__ bucket, const float* __restrict__ scoreB,
    _Float16* __restrict__ partial, float* __restrict__ out, int B) {
  int e = blockIdx.z;
  int cnt = counts[e * 32];
  int m0 = blockIdx.x * BM;
  if (m0 >= cnt) return;
  int n0 = blockIdx.y * BN;

  __shared__ unsigned short As[BM * BK];
  __shared__ unsigned short Bvs[BN * BK];
  __shared__ unsigned short Bgs[BN * BK];
  __shared__ int tokS[BM];
  __shared__ float scS[BM];

  int tid = threadIdx.x;
  if (tid < BM) {
    int gr = m0 + tid;
    bool vld = gr < cnt;
    tokS[tid] = vld ? bucket[e * CAP + gr] : 0;
    scS[tid] = vld ? scoreB[e * CAP + gr] : 0.0f;  // padded rows contribute 0
  }
  __syncthreads();

  int wid = tid >> 6, lane = tid & 63;
  int wm = wid & 1, wn = wid >> 1;
  int quad = lane >> 4, lr = lane & 15;

  const unsigned short* Bv0 = Wvt + (size_t)(e * H_DIM + n0) * D_DIM;
  const unsigned short* Bg0 = Wgt + (size_t)(e * H_DIM + n0) * D_DIM;

  // per-lane source pointers (fixed across kt; advance by BK halves per iter)
  int cswh = ((lane & 7) ^ (lane >> 3)) * 8;  // swizzled k-offset in halves
  const unsigned short *pA[4], *pBv[4], *pBg[4];
  char *lD[4];
#pragma unroll
  for (int i = 0; i < 4; i++) {
    int W = wid * 4 + i;
    int row = W * 8 + (lane >> 3);
    pA[i] = xh + (size_t)tokS[row] * D_DIM + cswh;
    pBv[i] = Bv0 + (size_t)row * D_DIM + cswh;
    pBg[i] = Bg0 + (size_t)row * D_DIM + cswh;
    lD[i] = (char*)nullptr + W * 1024;  // byte offset within each tile
  }

  f4v accv[4][4], accg[4][4];
#pragma unroll
  for (int a = 0; a < 4; a++)
#pragma unroll
    for (int bb = 0; bb < 4; bb++) {
      f4v z = {0.f, 0.f, 0.f, 0.f};
      accv[a][bb] = z;
      accg[a][bb] = z;
    }

  for (int kt = 0; kt < D_DIM / BK; kt++) {
#pragma unroll
    for (int i = 0; i < 4; i++) {
      size_t w = (size_t)(lD[i] - (char*)nullptr);
      gl2lds16(pA[i], (char*)As + w);
      gl2lds16(pBv[i], (char*)Bvs + w);
      gl2lds16(pBg[i], (char*)Bgs + w);
      pA[i] += BK; pBv[i] += BK; pBg[i] += BK;
    }
    __syncthreads();  // drains vmcnt: all 48 KB staged

    h8v af[4][2], bfr[4][2];
#pragma unroll
    for (int fm = 0; fm < 4; fm++)
#pragma unroll
      for (int s = 0; s < 2; s++) {
        int row = wm * 64 + fm * 16 + lr;
        int c = s * 4 + quad;
        af[fm][s] = *(const h8v*)(As + row * BK + ((c ^ (row & 7)) * 8));
      }
#pragma unroll
    for (int fn = 0; fn < 4; fn++)
#pragma unroll
      for (int s = 0; s < 2; s++) {
        int row = wn * 64 + fn * 16 + lr;
        int c = s * 4 + quad;
        bfr[fn][s] = *(const h8v*)(Bvs + row * BK + ((c ^ (row & 7)) * 8));
      }
#pragma unroll
    for (int fm = 0; fm < 4; fm++)
#pragma unroll
      for (int fn = 0; fn < 4; fn++)
#pragma unroll
        for (int s = 0; s < 2; s++)
          accv[fm][fn] = __builtin_amdgcn_mfma_f32_16x16x32_f16(
              af[fm][s], bfr[fn][s], accv[fm][fn], 0, 0, 0);
#pragma unroll
    for (int fn = 0; fn < 4; fn++)
#pragma unroll
      for (int s = 0; s < 2; s++) {
        int row = wn * 64 + fn * 16 + lr;
        int c = s * 4 + quad;
        bfr[fn][s] = *(const h8v*)(Bgs + row * BK + ((c ^ (row & 7)) * 8));
      }
#pragma unroll
    for (int fm = 0; fm < 4; fm++)
#pragma unroll
      for (int fn = 0; fn < 4; fn++)
#pragma unroll
        for (int s = 0; s < 2; s++)
          accg[fm][fn] = __builtin_amdgcn_mfma_f32_16x16x32_f16(
              af[fm][s], bfr[fn][s], accg[fm][fn], 0, 0, 0);
    __syncthreads();  // all waves done reading before next kt's DMA
  }

  // epilogue: act = v * sigmoid(g) * score
  // C/D layout: col = lane&15, row = quad*4 + reg  [measured m89/m91]
#pragma unroll
  for (int fm = 0; fm < 4; fm++) {
#pragma unroll
    for (int r = 0; r < 4; r++) {
      int row = wm * 64 + fm * 16 + quad * 4 + r;
      float sc = scS[row];
      if (USE_PARTIAL) {
        int slot = e * CAP + m0 + row;  // padded rows: sc=0 into never-read slots
        _Float16* pr = partial + (size_t)slot * H_DIM;
#pragma unroll
        for (int fn = 0; fn < 4; fn++) {
          int col = n0 + wn * 64 + fn * 16 + lr;
          float v = accv[fm][fn][r];
          float g = accg[fm][fn][r];
          pr[col] = (_Float16)(v * sc / (1.0f + __expf(-g)));
        }
      } else {
        int tok = tokS[row];
#pragma unroll
        for (int fn = 0; fn < 4; fn++) {
          int col = n0 + wn * 64 + fn * 16 + lr;
          float v = accv[fm][fn][r];
          float g = accg[fm][fn][r];
          atomicAdd(&out[(size_t)tok * H_DIM + col], v * sc / (1.0f + __expf(-g)));
        }
      }
    }
  }
}

// ---------------- phase 3: gather (out[b] = partial[s0] + partial[s1]) ----------
__global__ __launch_bounds__(256) void gather_kernel(
    const _Float16* __restrict__ partial, const int* __restrict__ slotOf,
    float* __restrict__ out) {
  int b = blockIdx.x * 2 + (threadIdx.x >> 7);  // 2 tokens/block
  int t = threadIdx.x & 127;                     // 8 halves per thread
  int s0 = slotOf[b * 2], s1 = slotOf[b * 2 + 1];
  if ((unsigned)s0 >= E_NUM * CAP) s0 = 0;  // poison guard (overflow ~impossible)
  if ((unsigned)s1 >= E_NUM * CAP) s1 = 0;
  h8v a = ((const h8v*)(partial + (size_t)s0 * H_DIM))[t];
  h8v c = ((const h8v*)(partial + (size_t)s1 * H_DIM))[t];
  float4 o0, o1;
  o0.x = (float)a[0] + (float)c[0];
  o0.y = (float)a[1] + (float)c[1];
  o0.z = (float)a[2] + (float)c[2];
  o0.w = (float)a[3] + (float)c[3];
  o1.x = (float)a[4] + (float)c[4];
  o1.y = (float)a[5] + (float)c[5];
  o1.z = (float)a[6] + (float)c[6];
  o1.w = (float)a[7] + (float)c[7];
  float4* op = (float4*)(out + (size_t)b * H_DIM);
  op[t * 2] = o0;
  op[t * 2 + 1] = o1;
}

extern "C" void kernel_launch(void* const* d_in, const int* in_sizes, int n_in,
                              void* d_out, int out_size, void* d_ws, size_t ws_size,
                              hipStream_t stream) {
  const float* x = (const float*)d_in[0];
  const float* Wv = (const float*)d_in[1];
  const float* Wg = (const float*)d_in[2];
  const float* gw = (const float*)d_in[3];
  const float* gb = (const float*)d_in[4];
  float* out = (float*)d_out;
  const int B = in_sizes[0] / D_DIM;  // 16384

  char* ws = (char*)d_ws;
  unsigned short* xh = (unsigned short*)ws;                       // 32 MB
  size_t off = (size_t)B * D_DIM * 2;
  unsigned short* Wvt = (unsigned short*)(ws + off);              // 16 MB
  off += (size_t)E_NUM * H_DIM * D_DIM * 2;
  unsigned short* Wgt = (unsigned short*)(ws + off);              // 16 MB
  off += (size_t)E_NUM * H_DIM * D_DIM * 2;
  int* counts = (int*)(ws + off);                                 // 8 padded counters
  off += 4096;
  int* bucket = (int*)(ws + off);                                 // E*CAP ints
  off += (size_t)E_NUM * CAP * 4;
  float* scoreB = (float*)(ws + off);                             // E*CAP floats
  off += (size_t)E_NUM * CAP * 4;
  int* slotOf = (int*)(ws + off);                                 // B*2 ints
  off += (size_t)B * 2 * 4;
  _Float16* partial = (_Float16*)(ws + off);                      // E*CAP*H fp16 = 80 MB
  size_t need = off + (size_t)E_NUM * CAP * H_DIM * 2;
  bool use_partial = ws_size >= need;

  hipMemsetAsync(counts, 0, 4096, stream);
  if (!use_partial) hipMemsetAsync(d_out, 0, (size_t)out_size * 4, stream);

  router_kernel<<<B / RT_TOK, 256, 0, stream>>>(
      (const float4*)x, (const float4*)gw, gb, counts, bucket, scoreB, slotOf,
      (ushort4*)xh, B);
  transpose_w_kernel<<<dim3(H_DIM / 64, D_DIM / 64, 2 * E_NUM), 256, 0, stream>>>(
      Wv, Wg, Wvt, Wgt);
  if (use_partial) {
    moe_gemm_kernel<true><<<dim3(CAP / BM, H_DIM / BN, E_NUM), 256, 0, stream>>>(
        xh, Wvt, Wgt, counts, bucket, scoreB, partial, out, B);
    gather_kernel<<<B / 2, 256, 0, stream>>>(partial, slotOf, out);
  } else {
    moe_gemm_kernel<false><<<dim3(CAP / BM, H_DIM / BN, E_NUM), 256, 0, stream>>>(
        xh, Wvt, Wgt, counts, bucket, scoreB, partial, out, B);
  }
}